// Round 8
// baseline (333.600 us; speedup 1.0000x reference)
//
#include <hip/hip_runtime.h>
#include <hip/hip_bf16.h>

// Problem constants (B=1)
#define T_ 8
#define H_ 64
#define W_ 64
#define C_ 64
#define HW_ (H_ * W_)          // 4096
#define THW_ (T_ * H_ * W_)    // 32768
#define KTAPS 27
#define KDIM (C_ * KTAPS)      // 1728
#define NOFF 54
#define CHS 70                 // padded LDS channel stride (bf16): 35 dwords, gcd(35,32)=1

typedef __bf16 bf16x8 __attribute__((ext_vector_type(8)));
typedef float floatx4 __attribute__((ext_vector_type(4)));

// ---------------------------------------------------------------------------
// prep: swizzle weights into MFMA B-fragment order so kernel B-loads are
// wave-uniform-base + lane*16B (fully coalesced).
//  ws[tap*4096 + wv*1024 + s*512 + lane*8 + j]
//    = W[co = wv*16 + (lane&15)][cin = s*32 + (lane>>4)*8 + j][tap]
// ---------------------------------------------------------------------------
__global__ void prep_kernel(const float* __restrict__ w1, const float* __restrict__ woff,
                            const float* __restrict__ wd, const float* __restrict__ wr,
                            __hip_bfloat16* __restrict__ w1s, __hip_bfloat16* __restrict__ woffs,
                            __hip_bfloat16* __restrict__ wds, __hip_bfloat16* __restrict__ wrs) {
    int i = blockIdx.x * 256 + threadIdx.x;
    if (i < C_ * KDIM) {
        int j = i & 7, lane = (i >> 3) & 63, s = (i >> 9) & 1, wv = (i >> 10) & 3, tap = i >> 12;
        int co = wv * 16 + (lane & 15);
        int cin = s * 32 + (lane >> 4) * 8 + j;
        int src = (co * C_ + cin) * KTAPS + tap;
        w1s[i] = __float2bfloat16(w1[src]);
        woffs[i] = (co < NOFF) ? __float2bfloat16(woff[src]) : __float2bfloat16(0.f);
        wds[i] = __float2bfloat16(wd[src]);
    }
    if (i < C_ * C_) {
        int j = i & 7, lane = (i >> 3) & 63, s = (i >> 9) & 1, wv = i >> 10;
        int co = wv * 16 + (lane & 15);
        int cin = s * 32 + (lane >> 4) * 8 + j;
        wrs[i] = __float2bfloat16(wr[co * C_ + cin]);
    }
}

// ---------------------------------------------------------------------------
// x (64,T,H,W) fp32 cf -> xcl (T,H,W,64) bf16 cl, via LDS 64x64 transpose tile
// ---------------------------------------------------------------------------
__global__ __launch_bounds__(256) void to_cl_kernel(const float* __restrict__ x,
                                                    __hip_bfloat16* __restrict__ xcl) {
    __shared__ float tile[64][65];
    const int pos0 = blockIdx.x * 64;
    const int tid = threadIdx.x;
    for (int i = tid; i < 4096; i += 256) {
        int ch = i >> 6, p = i & 63;
        tile[ch][p] = x[ch * THW_ + pos0 + p];
    }
    __syncthreads();
    for (int i = tid; i < 4096; i += 256) {
        int p = i >> 6, ch = i & 63;
        xcl[(pos0 + p) * C_ + ch] = __float2bfloat16(tile[ch][p]);
    }
}

// ---------------------------------------------------------------------------
// MFMA implicit-GEMM 3x3x3 conv, pad=1. Block=(t,h,w-half): 32 pos x 64 co.
//  1 barrier/row: stage row r+1 post-barrier while MFMAing row r.
//  A prefetched 2 rows ahead (regs), B 1 row ahead (coalesced swizzled loads).
// ---------------------------------------------------------------------------
template <bool CONV1>
__global__ __launch_bounds__(256) void conv_mfma_kernel(
    const __hip_bfloat16* __restrict__ in_cl,
    const __hip_bfloat16* __restrict__ wTs,   // swizzled (27*4096)
    const float* __restrict__ bias,
    __hip_bfloat16* __restrict__ out_cl_b16,  // CONV1: (T,H,W,64)
    float* __restrict__ out_cf,               // !CONV1: (NCO,T,H,W)
    int nco) {
    __shared__ float smem[2380];              // 2 x (34*70) bf16 = 9520B; reused ts[32][68]
    __hip_bfloat16* Ab = (__hip_bfloat16*)smem;

    const int tid = threadIdx.x;
    const int wv = tid >> 6;
    const int lane = tid & 63;
    const int l15 = lane & 15;
    const int quad = lane >> 4;
    const int wh = blockIdx.x & 1;
    const int h = (blockIdx.x >> 1) & 63;
    const int t = blockIdx.x >> 7;
    const int w0 = wh * 32;
    const int n = wv * 16 + l15;
    const int slot = tid >> 2;                // staging slot 0..33 (threads 0..135)
    const int c16 = tid & 3;
    const bool stager = tid < 136;

    floatx4 acc[2];
#pragma unroll
    for (int m = 0; m < 2; ++m) acc[m] = (floatx4){0.f, 0.f, 0.f, 0.f};

    const int ktlo = (t == 0) ? 1 : 0;
    const int kthi = (t == T_ - 1) ? 2 : 3;
    const int nr = (kthi - ktlo) * 3;         // 6 or 9 rows

    bf16x8 ra = {}, rb = {};
    auto load_row = [&](int r, bf16x8& a, bf16x8& b) {
        a = (bf16x8){};
        b = (bf16x8){};
        if (!stager) return;
        const int kt = ktlo + r / 3, kh = r % 3;
        const int h_in = h - 1 + kh;
        const int t_in = t - 1 + kt;
        const int w_in = w0 - 1 + slot;
        if ((unsigned)h_in < H_ && (unsigned)w_in < W_) {
            const __hip_bfloat16* p = in_cl + ((t_in * HW_ + h_in * W_) + w_in) * C_ + c16 * 16;
            a = *(const bf16x8*)(p);
            b = *(const bf16x8*)(p + 8);
        }
    };

    bf16x8 cb[6], nb[6];
    const __hip_bfloat16* wbase = wTs + wv * 1024 + lane * 8;
    auto loadB = [&](int r, bf16x8* B) {
        const int kt = ktlo + r / 3, kh = r % 3;
        const int tapb = kt * 9 + kh * 3;
#pragma unroll
        for (int kw = 0; kw < 3; ++kw) {
            const __hip_bfloat16* p = wbase + (tapb + kw) * 4096;
            B[kw * 2] = *(const bf16x8*)(p);
            B[kw * 2 + 1] = *(const bf16x8*)(p + 512);
        }
    };

    // prologue: stage row 0, prefetch row 1 (A) and rows 0,1 (B)
    load_row(0, ra, rb);
    loadB(0, cb);
    if (stager) {
        *(bf16x8*)&Ab[slot * CHS + c16 * 16] = ra;
        *(bf16x8*)&Ab[slot * CHS + c16 * 16 + 8] = rb;
    }
    load_row(1, ra, rb);
    loadB(1, nb);
    __syncthreads();

    for (int r = 0; r < nr; ++r) {
        __hip_bfloat16* buf = Ab + (r & 1) * 34 * CHS;
        if (r + 1 < nr) {                      // stage next row into other buffer
            __hip_bfloat16* bufn = Ab + ((r + 1) & 1) * 34 * CHS;
            if (stager) {
                *(bf16x8*)&bufn[slot * CHS + c16 * 16] = ra;
                *(bf16x8*)&bufn[slot * CHS + c16 * 16 + 8] = rb;
            }
            if (r + 2 < nr) load_row(r + 2, ra, rb);
        }
#pragma unroll
        for (int kw = 0; kw < 3; ++kw) {
            const bf16x8 b0 = cb[kw * 2];
            const bf16x8 b1 = cb[kw * 2 + 1];
#pragma unroll
            for (int m = 0; m < 2; ++m) {
                const __hip_bfloat16* ap = buf + (m * 16 + l15 + kw) * CHS + quad * 8;
                const bf16x8 a0 = *(const bf16x8*)(ap);
                const bf16x8 a1 = *(const bf16x8*)(ap + 32);
                acc[m] = __builtin_amdgcn_mfma_f32_16x16x32_bf16(a0, b0, acc[m], 0, 0, 0);
                acc[m] = __builtin_amdgcn_mfma_f32_16x16x32_bf16(a1, b1, acc[m], 0, 0, 0);
            }
        }
#pragma unroll
        for (int q2 = 0; q2 < 6; ++q2) cb[q2] = nb[q2];
        if (r + 2 < nr) loadB(r + 2, nb);
        __syncthreads();
    }

    const int posbase = t * HW_ + h * W_ + w0;

    if constexpr (CONV1) {
        float* ts = smem;                      // [32 pos][68 ch]
        const float bv = bias[n];
#pragma unroll
        for (int m = 0; m < 2; ++m)
#pragma unroll
            for (int r = 0; r < 4; ++r) {
                float v = acc[m][r] + bv;
                v = (v >= 0.f) ? v : 0.01f * v;
                ts[(m * 16 + quad * 4 + r) * 68 + n] = v;
            }
        __syncthreads();
#pragma unroll
        for (int c = 0; c < 2; ++c) {
            const int flat4 = c * 256 + tid;
            const int w = flat4 >> 4, cg = flat4 & 15;
            const float4 v4 = *(const float4*)&ts[w * 68 + cg * 4];
            __hip_bfloat16 hb[4] = {__float2bfloat16(v4.x), __float2bfloat16(v4.y),
                                    __float2bfloat16(v4.z), __float2bfloat16(v4.w)};
            *(uint2*)&out_cl_b16[(posbase + w) * C_ + cg * 4] = *(const uint2*)hb;
        }
    } else {
        if (n < nco) {
            const float bv = bias[n];
#pragma unroll
            for (int m = 0; m < 2; ++m) {
                floatx4 v = acc[m];
                v[0] += bv; v[1] += bv; v[2] += bv; v[3] += bv;
                *(floatx4*)&out_cf[n * THW_ + posbase + m * 16 + quad * 4] = v;
            }
        }
    }
}

// ---------------------------------------------------------------------------
// MFMA deformable conv, cooperative LDS-staged A, 2-tap-deep gather pipeline,
// swizzled coalesced B with 1-tap prefetch, fused 1x1 MFMA residual.
// FIX vs R7: gather slot parity must be RELATIVE to k0 (kr = k - k0); absolute
// parity clobbered the pending tap for t=0 blocks where k0=9 is odd.
// ---------------------------------------------------------------------------
struct Gath {
    bf16x8 c00, c01, c10, c11;
    float w00, w01, w10, w11;
};

__global__ __launch_bounds__(256) void deform_mfma_kernel(
    const __hip_bfloat16* __restrict__ y1b, const float* __restrict__ off,
    const __hip_bfloat16* __restrict__ wds, const float* __restrict__ bd,
    const __hip_bfloat16* __restrict__ xclb, const __hip_bfloat16* __restrict__ wrs,
    const float* __restrict__ br, float* __restrict__ out) {
    __shared__ __hip_bfloat16 Abuf[2][32 * CHS];     // 8960 B

    const int tid = threadIdx.x;
    const int wv = tid >> 6;
    const int lane = tid & 63;
    const int l15 = lane & 15;
    const int quad = lane >> 4;
    const int wh = blockIdx.x & 1;
    const int h = (blockIdx.x >> 1) & 63;
    const int t = blockIdx.x >> 7;
    const int w0 = wh * 32;
    const int n = wv * 16 + l15;
    const int posbase = t * HW_ + h * W_ + w0;
    const int cpos = tid >> 3;               // position 0..31
    const int c8 = tid & 7;                  // 8-ch chunk

    floatx4 acc[2], racc[2];
#pragma unroll
    for (int m = 0; m < 2; ++m) {
        acc[m] = (floatx4){0.f, 0.f, 0.f, 0.f};
        racc[m] = (floatx4){0.f, 0.f, 0.f, 0.f};
    }

    // ---- residual 1x1 conv on x (swizzled B, coalesced) ----
    {
        const bf16x8 rb0 = *(const bf16x8*)(wrs + wv * 1024 + lane * 8);
        const bf16x8 rb1 = *(const bf16x8*)(wrs + wv * 1024 + lane * 8 + 512);
#pragma unroll
        for (int m = 0; m < 2; ++m) {
            const __hip_bfloat16* ap = xclb + (posbase + m * 16 + l15) * C_ + quad * 8;
            const bf16x8 a0 = *(const bf16x8*)(ap);
            const bf16x8 a1 = *(const bf16x8*)(ap + 32);
            racc[m] = __builtin_amdgcn_mfma_f32_16x16x32_bf16(a0, rb0, racc[m], 0, 0, 0);
            racc[m] = __builtin_amdgcn_mfma_f32_16x16x32_bf16(a1, rb1, racc[m], 0, 0, 0);
        }
    }

    const int k0 = (t == 0) ? 9 : 0;
    const int k1 = (t == T_ - 1) ? 18 : KTAPS;

    auto load_off = [&](int k, float& dh, float& dw) {
        dh = off[(2 * k) * THW_ + posbase + cpos];
        dw = off[(2 * k + 1) * THW_ + posbase + cpos];
    };
    auto gather = [&](int k, float dh, float dw, Gath& g) {
        const int kt = k / 9, kh = (k / 3) % 3, kw = k % 3;
        const int t_in = t - 1 + kt;
        const float hs = (float)(h - 1 + kh) + dh;
        const float wsv = (float)(w0 + cpos - 1 + kw) + dw;
        const float h0f = floorf(hs), w0f = floorf(wsv);
        const float fh = hs - h0f, fw = wsv - w0f;
        const int h0i = (int)h0f, w0i = (int)w0f;
        const int h1i = h0i + 1, w1i = w0i + 1;
        const float m_h0 = ((unsigned)h0i < H_) ? 1.f : 0.f;
        const float m_h1 = ((unsigned)h1i < H_) ? 1.f : 0.f;
        const float m_w0 = ((unsigned)w0i < W_) ? 1.f : 0.f;
        const float m_w1 = ((unsigned)w1i < W_) ? 1.f : 0.f;
        g.w00 = (1.f - fh) * (1.f - fw) * m_h0 * m_w0;
        g.w01 = (1.f - fh) * fw * m_h0 * m_w1;
        g.w10 = fh * (1.f - fw) * m_h1 * m_w0;
        g.w11 = fh * fw * m_h1 * m_w1;
        const int h0c = min(max(h0i, 0), H_ - 1);
        const int h1c = min(max(h1i, 0), H_ - 1);
        const int w0c = min(max(w0i, 0), W_ - 1);
        const int w1c = min(max(w1i, 0), W_ - 1);
        const int tb = t_in * HW_;
        g.c00 = *(const bf16x8*)(y1b + (tb + h0c * W_ + w0c) * C_ + c8 * 8);
        g.c01 = *(const bf16x8*)(y1b + (tb + h0c * W_ + w1c) * C_ + c8 * 8);
        g.c10 = *(const bf16x8*)(y1b + (tb + h1c * W_ + w0c) * C_ + c8 * 8);
        g.c11 = *(const bf16x8*)(y1b + (tb + h1c * W_ + w1c) * C_ + c8 * 8);
    };
    auto blend = [&](const Gath& g, bf16x8& o) {
        union U { bf16x8 v; __hip_bfloat16 e[8]; };
        U a00, a01, a10, a11, r;
        a00.v = g.c00; a01.v = g.c01; a10.v = g.c10; a11.v = g.c11;
#pragma unroll
        for (int j = 0; j < 8; ++j) {
            float f = g.w00 * __bfloat162float(a00.e[j]) + g.w01 * __bfloat162float(a01.e[j]) +
                      g.w10 * __bfloat162float(a10.e[j]) + g.w11 * __bfloat162float(a11.e[j]);
            r.e[j] = __float2bfloat16(f);
        }
        o = r.v;
    };
    auto loadBd = [&](int k, bf16x8* B) {
        const __hip_bfloat16* p = wds + k * 4096 + wv * 1024 + lane * 8;
        B[0] = *(const bf16x8*)(p);
        B[1] = *(const bf16x8*)(p + 512);
    };

    // ---- pipeline prologue: gathers 2 taps deep, B 1 tap deep ----
    // Invariant: g[(tap - k0) & 1] holds tap's gather until blended.
    Gath g[2];
    bf16x8 bl;
    bf16x8 cbd[2], nbd[2];
    float oh, ow, oh1, ow1, oh2, ow2;
    load_off(k0, oh, ow);
    load_off(k0 + 1, oh1, ow1);
    load_off(k0 + 2, oh2, ow2);
    gather(k0, oh, ow, g[0]);
    gather(k0 + 1, oh1, ow1, g[1]);
    loadBd(k0, cbd);
    loadBd(k0 + 1, nbd);
    blend(g[0], bl);

    // ---- main loop: 1 barrier per tap ----
    for (int k = k0; k < k1; ++k) {
        const int kr = k - k0;                        // RELATIVE parity (the R7 fix)
        __hip_bfloat16* buf = Abuf[kr & 1];
        *(bf16x8*)&buf[cpos * CHS + c8 * 8] = bl;
        if (k + 2 < k1) {
            gather(k + 2, oh2, ow2, g[kr & 1]);       // slot of tap k: already consumed
            if (k + 3 < k1) load_off(k + 3, oh2, ow2);
        }
        __syncthreads();

        const bf16x8 b0 = cbd[0];
        const bf16x8 b1 = cbd[1];
#pragma unroll
        for (int m = 0; m < 2; ++m) {
            const __hip_bfloat16* ap = buf + (m * 16 + l15) * CHS + quad * 8;
            const bf16x8 a0 = *(const bf16x8*)(ap);
            const bf16x8 a1 = *(const bf16x8*)(ap + 32);
            acc[m] = __builtin_amdgcn_mfma_f32_16x16x32_bf16(a0, b0, acc[m], 0, 0, 0);
            acc[m] = __builtin_amdgcn_mfma_f32_16x16x32_bf16(a1, b1, acc[m], 0, 0, 0);
        }
        if (k + 1 < k1) {
            blend(g[(kr + 1) & 1], bl);               // tap k+1's slot
            cbd[0] = nbd[0]; cbd[1] = nbd[1];
            if (k + 2 < k1) loadBd(k + 2, nbd);
        }
    }

    // ---- epilogue: lrelu(deform + bd) + (residual + br) ----
    const float bdv = bd[n];
    const float brv = br[n];
#pragma unroll
    for (int m = 0; m < 2; ++m) {
        floatx4 o;
#pragma unroll
        for (int r = 0; r < 4; ++r) {
            float v = acc[m][r] + bdv;
            v = (v >= 0.f) ? v : 0.01f * v;
            o[r] = v + racc[m][r] + brv;
        }
        *(floatx4*)&out[n * THW_ + posbase + m * 16 + quad * 4] = o;
    }
}

// ---------------------------------------------------------------------------
extern "C" void kernel_launch(void* const* d_in, const int* in_sizes, int n_in,
                              void* d_out, int out_size, void* d_ws, size_t ws_size,
                              hipStream_t stream) {
    const float* x    = (const float*)d_in[0];
    const float* W1   = (const float*)d_in[1];
    const float* b1   = (const float*)d_in[2];
    const float* Woff = (const float*)d_in[3];
    const float* boff = (const float*)d_in[4];
    const float* Wd   = (const float*)d_in[5];
    const float* bd   = (const float*)d_in[6];
    const float* Wr   = (const float*)d_in[7];
    const float* br   = (const float*)d_in[8];
    float* out = (float*)d_out;

    float* ws = (float*)d_ws;
    float* offcf = ws;                                         // 1,769,472 f
    __hip_bfloat16* xclb  = (__hip_bfloat16*)(ws + 1769472);   // 2,097,152 bf16
    __hip_bfloat16* y1b   = (__hip_bfloat16*)(ws + 2818048);   // 2,097,152 bf16
    __hip_bfloat16* w1s   = (__hip_bfloat16*)(ws + 3866624);   //   110,592 bf16
    __hip_bfloat16* woffs = (__hip_bfloat16*)(ws + 3921920);   //   110,592 bf16
    __hip_bfloat16* wdsb  = (__hip_bfloat16*)(ws + 3977216);   //   110,592 bf16
    __hip_bfloat16* wrsb  = (__hip_bfloat16*)(ws + 4032512);   //     4,096 bf16
    // total ~16.1 MB

    prep_kernel<<<(C_ * KDIM + 255) / 256, 256, 0, stream>>>(
        W1, Woff, Wd, Wr, w1s, woffs, wdsb, wrsb);

    to_cl_kernel<<<THW_ / 64, 256, 0, stream>>>(x, xclb);

    conv_mfma_kernel<true><<<dim3(T_ * H_ * 2), 256, 0, stream>>>(
        xclb, w1s, b1, y1b, nullptr, 64);

    conv_mfma_kernel<false><<<dim3(T_ * H_ * 2), 256, 0, stream>>>(
        y1b, woffs, boff, nullptr, offcf, NOFF);

    deform_mfma_kernel<<<dim3(T_ * H_ * 2), 256, 0, stream>>>(
        y1b, offcf, wdsb, bd, xclb, wrsb, br, out);
}

// Round 9
// 247.721 us; speedup vs baseline: 1.3467x; 1.3467x over previous
//
#include <hip/hip_runtime.h>
#include <hip/hip_bf16.h>

// Problem constants (B=1)
#define T_ 8
#define H_ 64
#define W_ 64
#define C_ 64
#define HW_ (H_ * W_)          // 4096
#define THW_ (T_ * H_ * W_)    // 32768
#define KTAPS 27
#define KDIM (C_ * KTAPS)      // 1728
#define NOFF 54
#define CHS 70                 // padded LDS channel stride (bf16): 35 dwords, gcd(35,32)=1

typedef __bf16 bf16x8 __attribute__((ext_vector_type(8)));
typedef float floatx4 __attribute__((ext_vector_type(4)));

// ---------------------------------------------------------------------------
// prep: swizzle weights into MFMA B-fragment order so kernel B-loads are
// wave-uniform-base + lane*16B (fully coalesced).
//  ws[tap*4096 + wv*1024 + s*512 + lane*8 + j]
//    = W[co = wv*16 + (lane&15)][cin = s*32 + (lane>>4)*8 + j][tap]
// ---------------------------------------------------------------------------
__global__ void prep_kernel(const float* __restrict__ w1, const float* __restrict__ woff,
                            const float* __restrict__ wd, const float* __restrict__ wr,
                            __hip_bfloat16* __restrict__ w1s, __hip_bfloat16* __restrict__ woffs,
                            __hip_bfloat16* __restrict__ wds, __hip_bfloat16* __restrict__ wrs) {
    int i = blockIdx.x * 256 + threadIdx.x;
    if (i < C_ * KDIM) {
        int j = i & 7, lane = (i >> 3) & 63, s = (i >> 9) & 1, wv = (i >> 10) & 3, tap = i >> 12;
        int co = wv * 16 + (lane & 15);
        int cin = s * 32 + (lane >> 4) * 8 + j;
        int src = (co * C_ + cin) * KTAPS + tap;
        w1s[i] = __float2bfloat16(w1[src]);
        woffs[i] = (co < NOFF) ? __float2bfloat16(woff[src]) : __float2bfloat16(0.f);
        wds[i] = __float2bfloat16(wd[src]);
    }
    if (i < C_ * C_) {
        int j = i & 7, lane = (i >> 3) & 63, s = (i >> 9) & 1, wv = i >> 10;
        int co = wv * 16 + (lane & 15);
        int cin = s * 32 + (lane >> 4) * 8 + j;
        wrs[i] = __float2bfloat16(wr[co * C_ + cin]);
    }
}

// ---------------------------------------------------------------------------
// x (64,T,H,W) fp32 cf -> xcl (T,H,W,64) bf16 cl, via LDS 64x64 transpose tile
// ---------------------------------------------------------------------------
__global__ __launch_bounds__(256) void to_cl_kernel(const float* __restrict__ x,
                                                    __hip_bfloat16* __restrict__ xcl) {
    __shared__ float tile[64][65];
    const int pos0 = blockIdx.x * 64;
    const int tid = threadIdx.x;
    for (int i = tid; i < 4096; i += 256) {
        int ch = i >> 6, p = i & 63;
        tile[ch][p] = x[ch * THW_ + pos0 + p];
    }
    __syncthreads();
    for (int i = tid; i < 4096; i += 256) {
        int p = i >> 6, ch = i & 63;
        xcl[(pos0 + p) * C_ + ch] = __float2bfloat16(tile[ch][p]);
    }
}

// ---------------------------------------------------------------------------
// MFMA implicit-GEMM 3x3x3 conv, pad=1. Block=(t,h,w-half): 32 pos x 64 co.
//  1 barrier/row: stage row r+1 post-barrier while MFMAing row r.
//  A prefetched 2 rows ahead (regs), B 1 row ahead (coalesced swizzled loads).
// ---------------------------------------------------------------------------
template <bool CONV1>
__global__ __launch_bounds__(256) void conv_mfma_kernel(
    const __hip_bfloat16* __restrict__ in_cl,
    const __hip_bfloat16* __restrict__ wTs,   // swizzled (27*4096)
    const float* __restrict__ bias,
    __hip_bfloat16* __restrict__ out_cl_b16,  // CONV1: (T,H,W,64)
    float* __restrict__ out_cf,               // !CONV1: (NCO,T,H,W)
    int nco) {
    __shared__ float smem[2380];              // 2 x (34*70) bf16 = 9520B; reused ts[32][68]
    __hip_bfloat16* Ab = (__hip_bfloat16*)smem;

    const int tid = threadIdx.x;
    const int wv = tid >> 6;
    const int lane = tid & 63;
    const int l15 = lane & 15;
    const int quad = lane >> 4;
    const int wh = blockIdx.x & 1;
    const int h = (blockIdx.x >> 1) & 63;
    const int t = blockIdx.x >> 7;
    const int w0 = wh * 32;
    const int n = wv * 16 + l15;
    const int slot = tid >> 2;                // staging slot 0..33 (threads 0..135)
    const int c16 = tid & 3;
    const bool stager = tid < 136;

    floatx4 acc[2];
#pragma unroll
    for (int m = 0; m < 2; ++m) acc[m] = (floatx4){0.f, 0.f, 0.f, 0.f};

    const int ktlo = (t == 0) ? 1 : 0;
    const int kthi = (t == T_ - 1) ? 2 : 3;
    const int nr = (kthi - ktlo) * 3;         // 6 or 9 rows

    bf16x8 ra = {}, rb = {};
    auto load_row = [&](int r, bf16x8& a, bf16x8& b) {
        a = (bf16x8){};
        b = (bf16x8){};
        if (!stager) return;
        const int kt = ktlo + r / 3, kh = r % 3;
        const int h_in = h - 1 + kh;
        const int t_in = t - 1 + kt;
        const int w_in = w0 - 1 + slot;
        if ((unsigned)h_in < H_ && (unsigned)w_in < W_) {
            const __hip_bfloat16* p = in_cl + ((t_in * HW_ + h_in * W_) + w_in) * C_ + c16 * 16;
            a = *(const bf16x8*)(p);
            b = *(const bf16x8*)(p + 8);
        }
    };

    bf16x8 cb[6], nb[6];
    const __hip_bfloat16* wbase = wTs + wv * 1024 + lane * 8;
    auto loadB = [&](int r, bf16x8* B) {
        const int kt = ktlo + r / 3, kh = r % 3;
        const int tapb = kt * 9 + kh * 3;
#pragma unroll
        for (int kw = 0; kw < 3; ++kw) {
            const __hip_bfloat16* p = wbase + (tapb + kw) * 4096;
            B[kw * 2] = *(const bf16x8*)(p);
            B[kw * 2 + 1] = *(const bf16x8*)(p + 512);
        }
    };

    // prologue: stage row 0, prefetch row 1 (A) and rows 0,1 (B)
    load_row(0, ra, rb);
    loadB(0, cb);
    if (stager) {
        *(bf16x8*)&Ab[slot * CHS + c16 * 16] = ra;
        *(bf16x8*)&Ab[slot * CHS + c16 * 16 + 8] = rb;
    }
    load_row(1, ra, rb);
    loadB(1, nb);
    __syncthreads();

    for (int r = 0; r < nr; ++r) {
        __hip_bfloat16* buf = Ab + (r & 1) * 34 * CHS;
        if (r + 1 < nr) {                      // stage next row into other buffer
            __hip_bfloat16* bufn = Ab + ((r + 1) & 1) * 34 * CHS;
            if (stager) {
                *(bf16x8*)&bufn[slot * CHS + c16 * 16] = ra;
                *(bf16x8*)&bufn[slot * CHS + c16 * 16 + 8] = rb;
            }
            if (r + 2 < nr) load_row(r + 2, ra, rb);
        }
#pragma unroll
        for (int kw = 0; kw < 3; ++kw) {
            const bf16x8 b0 = cb[kw * 2];
            const bf16x8 b1 = cb[kw * 2 + 1];
#pragma unroll
            for (int m = 0; m < 2; ++m) {
                const __hip_bfloat16* ap = buf + (m * 16 + l15 + kw) * CHS + quad * 8;
                const bf16x8 a0 = *(const bf16x8*)(ap);
                const bf16x8 a1 = *(const bf16x8*)(ap + 32);
                acc[m] = __builtin_amdgcn_mfma_f32_16x16x32_bf16(a0, b0, acc[m], 0, 0, 0);
                acc[m] = __builtin_amdgcn_mfma_f32_16x16x32_bf16(a1, b1, acc[m], 0, 0, 0);
            }
        }
#pragma unroll
        for (int q2 = 0; q2 < 6; ++q2) cb[q2] = nb[q2];
        if (r + 2 < nr) loadB(r + 2, nb);
        __syncthreads();
    }

    const int posbase = t * HW_ + h * W_ + w0;

    if constexpr (CONV1) {
        float* ts = smem;                      // [32 pos][68 ch]
        const float bv = bias[n];
#pragma unroll
        for (int m = 0; m < 2; ++m)
#pragma unroll
            for (int r = 0; r < 4; ++r) {
                float v = acc[m][r] + bv;
                v = (v >= 0.f) ? v : 0.01f * v;
                ts[(m * 16 + quad * 4 + r) * 68 + n] = v;
            }
        __syncthreads();
#pragma unroll
        for (int c = 0; c < 2; ++c) {
            const int flat4 = c * 256 + tid;
            const int w = flat4 >> 4, cg = flat4 & 15;
            const float4 v4 = *(const float4*)&ts[w * 68 + cg * 4];
            __hip_bfloat16 hb[4] = {__float2bfloat16(v4.x), __float2bfloat16(v4.y),
                                    __float2bfloat16(v4.z), __float2bfloat16(v4.w)};
            *(uint2*)&out_cl_b16[(posbase + w) * C_ + cg * 4] = *(const uint2*)hb;
        }
    } else {
        if (n < nco) {
            const float bv = bias[n];
#pragma unroll
            for (int m = 0; m < 2; ++m) {
                floatx4 v = acc[m];
                v[0] += bv; v[1] += bv; v[2] += bv; v[3] += bv;
                *(floatx4*)&out_cf[n * THW_ + posbase + m * 16 + quad * 4] = v;
            }
        }
    }
}

// ---------------------------------------------------------------------------
// MFMA deformable conv. FIX vs R8: the 2-deep gather pipeline now uses NAMED
// slot variables (gA/gB) with a manually 2x-unrolled tap loop, so slots are
// selected at COMPILE TIME. R8's `Gath g[2]` + runtime `g[kr&1]` indexing
// forced the array into scratch -> 450+ MB of spill traffic (WRITE_SIZE 497MB).
// Invariant: even kr -> (Abuf[0], self=gA); odd kr -> (Abuf[1], self=gB).
// ---------------------------------------------------------------------------
struct Gath {
    bf16x8 c00, c01, c10, c11;
    float w00, w01, w10, w11;
};

__global__ __launch_bounds__(256) void deform_mfma_kernel(
    const __hip_bfloat16* __restrict__ y1b, const float* __restrict__ off,
    const __hip_bfloat16* __restrict__ wds, const float* __restrict__ bd,
    const __hip_bfloat16* __restrict__ xclb, const __hip_bfloat16* __restrict__ wrs,
    const float* __restrict__ br, float* __restrict__ out) {
    __shared__ __hip_bfloat16 Abuf[2][32 * CHS];     // 8960 B

    const int tid = threadIdx.x;
    const int wv = tid >> 6;
    const int lane = tid & 63;
    const int l15 = lane & 15;
    const int quad = lane >> 4;
    const int wh = blockIdx.x & 1;
    const int h = (blockIdx.x >> 1) & 63;
    const int t = blockIdx.x >> 7;
    const int w0 = wh * 32;
    const int n = wv * 16 + l15;
    const int posbase = t * HW_ + h * W_ + w0;
    const int cpos = tid >> 3;               // position 0..31
    const int c8 = tid & 7;                  // 8-ch chunk

    floatx4 acc[2], racc[2];
#pragma unroll
    for (int m = 0; m < 2; ++m) {
        acc[m] = (floatx4){0.f, 0.f, 0.f, 0.f};
        racc[m] = (floatx4){0.f, 0.f, 0.f, 0.f};
    }

    // ---- residual 1x1 conv on x (swizzled B, coalesced) ----
    {
        const bf16x8 rb0 = *(const bf16x8*)(wrs + wv * 1024 + lane * 8);
        const bf16x8 rb1 = *(const bf16x8*)(wrs + wv * 1024 + lane * 8 + 512);
#pragma unroll
        for (int m = 0; m < 2; ++m) {
            const __hip_bfloat16* ap = xclb + (posbase + m * 16 + l15) * C_ + quad * 8;
            const bf16x8 a0 = *(const bf16x8*)(ap);
            const bf16x8 a1 = *(const bf16x8*)(ap + 32);
            racc[m] = __builtin_amdgcn_mfma_f32_16x16x32_bf16(a0, rb0, racc[m], 0, 0, 0);
            racc[m] = __builtin_amdgcn_mfma_f32_16x16x32_bf16(a1, rb1, racc[m], 0, 0, 0);
        }
    }

    const int k0 = (t == 0) ? 9 : 0;
    const int k1 = (t == T_ - 1) ? 18 : KTAPS;

    auto load_off = [&](int k, float& dh, float& dw) {
        dh = off[(2 * k) * THW_ + posbase + cpos];
        dw = off[(2 * k + 1) * THW_ + posbase + cpos];
    };
    auto gather = [&](int k, float dh, float dw, Gath& g) {
        const int kt = k / 9, kh = (k / 3) % 3, kw = k % 3;
        const int t_in = t - 1 + kt;
        const float hs = (float)(h - 1 + kh) + dh;
        const float wsv = (float)(w0 + cpos - 1 + kw) + dw;
        const float h0f = floorf(hs), w0f = floorf(wsv);
        const float fh = hs - h0f, fw = wsv - w0f;
        const int h0i = (int)h0f, w0i = (int)w0f;
        const int h1i = h0i + 1, w1i = w0i + 1;
        const float m_h0 = ((unsigned)h0i < H_) ? 1.f : 0.f;
        const float m_h1 = ((unsigned)h1i < H_) ? 1.f : 0.f;
        const float m_w0 = ((unsigned)w0i < W_) ? 1.f : 0.f;
        const float m_w1 = ((unsigned)w1i < W_) ? 1.f : 0.f;
        g.w00 = (1.f - fh) * (1.f - fw) * m_h0 * m_w0;
        g.w01 = (1.f - fh) * fw * m_h0 * m_w1;
        g.w10 = fh * (1.f - fw) * m_h1 * m_w0;
        g.w11 = fh * fw * m_h1 * m_w1;
        const int h0c = min(max(h0i, 0), H_ - 1);
        const int h1c = min(max(h1i, 0), H_ - 1);
        const int w0c = min(max(w0i, 0), W_ - 1);
        const int w1c = min(max(w1i, 0), W_ - 1);
        const int tb = t_in * HW_;
        g.c00 = *(const bf16x8*)(y1b + (tb + h0c * W_ + w0c) * C_ + c8 * 8);
        g.c01 = *(const bf16x8*)(y1b + (tb + h0c * W_ + w1c) * C_ + c8 * 8);
        g.c10 = *(const bf16x8*)(y1b + (tb + h1c * W_ + w0c) * C_ + c8 * 8);
        g.c11 = *(const bf16x8*)(y1b + (tb + h1c * W_ + w1c) * C_ + c8 * 8);
    };
    auto blend = [&](const Gath& g, bf16x8& o) {
        union U { bf16x8 v; __hip_bfloat16 e[8]; };
        U a00, a01, a10, a11, r;
        a00.v = g.c00; a01.v = g.c01; a10.v = g.c10; a11.v = g.c11;
#pragma unroll
        for (int j = 0; j < 8; ++j) {
            float f = g.w00 * __bfloat162float(a00.e[j]) + g.w01 * __bfloat162float(a01.e[j]) +
                      g.w10 * __bfloat162float(a10.e[j]) + g.w11 * __bfloat162float(a11.e[j]);
            r.e[j] = __float2bfloat16(f);
        }
        o = r.v;
    };
    auto loadBd = [&](int k, bf16x8& B0, bf16x8& B1) {
        const __hip_bfloat16* p = wds + k * 4096 + wv * 1024 + lane * 8;
        B0 = *(const bf16x8*)(p);
        B1 = *(const bf16x8*)(p + 512);
    };

    // ---- named pipeline state (NO dynamically-indexed arrays) ----
    Gath gA, gB;
    bf16x8 bl;
    bf16x8 cb0, cb1, nb0, nb1;
    float oh2, ow2;

    // one tap step; s / gSelf / gOther resolved at compile time per call site
    auto step = [&](int k, __hip_bfloat16* buf, Gath& gSelf, Gath& gOther) {
        *(bf16x8*)&buf[cpos * CHS + c8 * 8] = bl;
        if (k + 2 < k1) {
            gather(k + 2, oh2, ow2, gSelf);           // tap k's slot: already consumed
            if (k + 3 < k1) load_off(k + 3, oh2, ow2);
        }
        __syncthreads();

        const bf16x8 b0 = cb0;
        const bf16x8 b1 = cb1;
#pragma unroll
        for (int m = 0; m < 2; ++m) {
            const __hip_bfloat16* ap = buf + (m * 16 + l15) * CHS + quad * 8;
            const bf16x8 a0 = *(const bf16x8*)(ap);
            const bf16x8 a1 = *(const bf16x8*)(ap + 32);
            acc[m] = __builtin_amdgcn_mfma_f32_16x16x32_bf16(a0, b0, acc[m], 0, 0, 0);
            acc[m] = __builtin_amdgcn_mfma_f32_16x16x32_bf16(a1, b1, acc[m], 0, 0, 0);
        }
        if (k + 1 < k1) {
            blend(gOther, bl);                        // tap k+1
            cb0 = nb0; cb1 = nb1;
            if (k + 2 < k1) loadBd(k + 2, nb0, nb1);
        }
    };

    // ---- prologue: gathers 2 taps deep, B 1 tap deep ----
    {
        float dh0, dw0, dh1, dw1;
        load_off(k0, dh0, dw0);
        load_off(k0 + 1, dh1, dw1);
        load_off(k0 + 2, oh2, ow2);
        gather(k0, dh0, dw0, gA);
        gather(k0 + 1, dh1, dw1, gB);
        loadBd(k0, cb0, cb1);
        loadBd(k0 + 1, nb0, nb1);
        blend(gA, bl);
    }

    // ---- main loop, 2x unrolled: even kr -> (buf0, gA), odd kr -> (buf1, gB)
    int k = k0;
    for (; k + 1 < k1; k += 2) {
        step(k, Abuf[0], gA, gB);
        step(k + 1, Abuf[1], gB, gA);
    }
    if (k < k1) step(k, Abuf[0], gA, gB);             // tail (nk odd: kr even -> gA/buf0)

    // ---- epilogue: lrelu(deform + bd) + (residual + br) ----
    const float bdv = bd[n];
    const float brv = br[n];
#pragma unroll
    for (int m = 0; m < 2; ++m) {
        floatx4 o;
#pragma unroll
        for (int r = 0; r < 4; ++r) {
            float v = acc[m][r] + bdv;
            v = (v >= 0.f) ? v : 0.01f * v;
            o[r] = v + racc[m][r] + brv;
        }
        *(floatx4*)&out[n * THW_ + posbase + m * 16 + quad * 4] = o;
    }
}

// ---------------------------------------------------------------------------
extern "C" void kernel_launch(void* const* d_in, const int* in_sizes, int n_in,
                              void* d_out, int out_size, void* d_ws, size_t ws_size,
                              hipStream_t stream) {
    const float* x    = (const float*)d_in[0];
    const float* W1   = (const float*)d_in[1];
    const float* b1   = (const float*)d_in[2];
    const float* Woff = (const float*)d_in[3];
    const float* boff = (const float*)d_in[4];
    const float* Wd   = (const float*)d_in[5];
    const float* bd   = (const float*)d_in[6];
    const float* Wr   = (const float*)d_in[7];
    const float* br   = (const float*)d_in[8];
    float* out = (float*)d_out;

    float* ws = (float*)d_ws;
    float* offcf = ws;                                         // 1,769,472 f
    __hip_bfloat16* xclb  = (__hip_bfloat16*)(ws + 1769472);   // 2,097,152 bf16
    __hip_bfloat16* y1b   = (__hip_bfloat16*)(ws + 2818048);   // 2,097,152 bf16
    __hip_bfloat16* w1s   = (__hip_bfloat16*)(ws + 3866624);   //   110,592 bf16
    __hip_bfloat16* woffs = (__hip_bfloat16*)(ws + 3921920);   //   110,592 bf16
    __hip_bfloat16* wdsb  = (__hip_bfloat16*)(ws + 3977216);   //   110,592 bf16
    __hip_bfloat16* wrsb  = (__hip_bfloat16*)(ws + 4032512);   //     4,096 bf16
    // total ~16.1 MB

    prep_kernel<<<(C_ * KDIM + 255) / 256, 256, 0, stream>>>(
        W1, Woff, Wd, Wr, w1s, woffs, wdsb, wrsb);

    to_cl_kernel<<<THW_ / 64, 256, 0, stream>>>(x, xclb);

    conv_mfma_kernel<true><<<dim3(T_ * H_ * 2), 256, 0, stream>>>(
        xclb, w1s, b1, y1b, nullptr, 64);

    conv_mfma_kernel<false><<<dim3(T_ * H_ * 2), 256, 0, stream>>>(
        y1b, woffs, boff, nullptr, offcf, NOFF);

    deform_mfma_kernel<<<dim3(T_ * H_ * 2), 256, 0, stream>>>(
        y1b, offcf, wdsb, bd, xclb, wrsb, br, out);
}